// Round 7
// baseline (967.796 us; speedup 1.0000x reference)
//
#include <hip/hip_runtime.h>

// WindowAttention: B_=4096, N=49, C=256, H=8, hd=32, nW=64
// ws layout (bf16): [q | k | v | pre] each SEG elements
//   q/k/v: plain (M=200704, 256) row-major, m = b*49+i, c = h*32+d
//          (GEMM-natural layout; q pre-scaled by hd^-0.5)
//   pre  : (B_, N, C) attention output before proj
// d_out doubles as scratch:
//   [0, 8.39MB)  : expanded (mask+bias) ADD tensor (nW*H, 64, 64) fp32
//   [10MB, ...)  : qkv_w converted to bf16 (768x256)
// proj_gemm fully overwrites d_out afterwards and reads none of it.
// proj_w (bf16) is converted AFTER attn into ws segment 0 (q, dead by then).
// x is read fp32 directly by qkv_gemm (cvt fused into A-staging).
#define SEG 51380224  // 4096*8*49*32 == 4096*49*256

typedef __attribute__((ext_vector_type(8))) __bf16 bf16x8;
typedef __attribute__((ext_vector_type(4))) __bf16 bf16x4;
typedef __attribute__((ext_vector_type(4))) float f32x4;

static __device__ __forceinline__ bf16x8 bzero8() {
    bf16x8 z;
#pragma unroll
    for (int u = 0; u < 8; ++u) z[u] = (__bf16)0.0f;
    return z;
}

// async global->LDS, 16B per lane; LDS dest is wave-uniform base + lane*16
static __device__ __forceinline__ void gl_lds16(const __bf16* g, __bf16* l) {
    __builtin_amdgcn_global_load_lds(
        (const __attribute__((address_space(1))) void*)g,
        (__attribute__((address_space(3))) void*)l, 16, 0, 0);
}

// ---------------------------------------------------------------------------
// K-1: fp32 -> bf16 bulk convert (small weights only now).
// ---------------------------------------------------------------------------
__global__ __launch_bounds__(256)
void cvt_bf16_k(const float* __restrict__ src, __bf16* __restrict__ dst, int n8)
{
    int i = blockIdx.x * 256 + threadIdx.x;
    const int stride = gridDim.x * 256;
    for (; i < n8; i += stride) {
        float4 a = *reinterpret_cast<const float4*>(src + (size_t)i * 8);
        float4 b = *reinterpret_cast<const float4*>(src + (size_t)i * 8 + 4);
        bf16x8 o;
        o[0] = (__bf16)a.x; o[1] = (__bf16)a.y; o[2] = (__bf16)a.z; o[3] = (__bf16)a.w;
        o[4] = (__bf16)b.x; o[5] = (__bf16)b.y; o[6] = (__bf16)b.z; o[7] = (__bf16)b.w;
        *reinterpret_cast<bf16x8*>(dst + (size_t)i * 8) = o;
    }
}

// ---------------------------------------------------------------------------
// K0: ADD[w*8+h][i][j] = mask[w][i][j] + bias[h][i][j]  (64x64, -1e30 pad)
// ---------------------------------------------------------------------------
__global__ __launch_bounds__(256)
void expand_add_k(const float* __restrict__ mask, const float* __restrict__ rpb,
                  float* __restrict__ add)
{
    const int wh = blockIdx.x;           // 0..511
    const int w = wh >> 3, h = wh & 7;
    for (int e = threadIdx.x; e < 4096; e += 256) {
        int i = e >> 6, j = e & 63;
        float v = -1e30f;
        if (i < 49 && j < 49) {
            int ih = i / 7, iw = i - ih * 7;
            int jh = j / 7, jw = j - jh * 7;
            int bidx = (ih - jh + 6) * 13 + (iw - jw + 6);
            v = mask[(size_t)w * 2401 + i * 49 + j] + rpb[bidx * 8 + h];
        }
        add[(size_t)wh * 4096 + e] = v;
    }
}

// ---------------------------------------------------------------------------
// K1: qkv = x(fp32) @ qkv_wb^T + qkv_b -> three (M,256) bf16 segments.
// 128x128 tile, BK=64, 4 waves, dbuf LDS.
// A: fused fp32->bf16 — nt f32x4 loads issued BEFORE compute (T14 split),
//    cvt + swizzled ds_write_b128 after compute, into the other buffer.
//    Writer puts logical c16 (ah*4+j) at phys (ah*4+j)^(row&7); reader XOR
//    (cl^(row&7)) recovers it (same involution as B).
// B: gl_lds with source-preswizzled column (unchanged).
// Epilogue: LDS-restaged coalesced 256B-segment stores, NON-TEMPORAL (the
// 301MB q/k/v stream exceeds L3 -> bypass write-allocate thrash).
// Grid: flat 9408; XCD-chunked bijective swizzle, n fastest (L2 panel reuse).
// ---------------------------------------------------------------------------
__global__ __launch_bounds__(256)
void qkv_gemm_k(const float* __restrict__ x, const __bf16* __restrict__ w,
                const float* __restrict__ bvec, __bf16* __restrict__ ws)
{
    __shared__ __bf16 As[2][128][64];
    __shared__ __bf16 Bs[2][128][64];
    const int tid  = threadIdx.x;
    const int nwg  = 1568 * 6;                     // 9408, % 8 == 0
    const int bid  = blockIdx.x;
    const int v    = (bid & 7) * (nwg >> 3) + (bid >> 3);
    const int mb   = v / 6, nb = v - mb * 6;
    const int m0   = mb * 128;
    const int n0   = nb * 128;
    const int wave = tid >> 6, lane = tid & 63;
    const int wm   = wave >> 1, wn = wave & 1;
    const int quad = lane >> 4, lm = lane & 15;

    // B staging geometry (gl_lds): issue i covers rows [i*32+wave*8,+8)
    const int srow = wave * 8 + (lane >> 3);
    const int scol = (((lane & 7) ^ (lane >> 3)) << 3);   // pre-swizzled source col

    // A staging geometry (reg): thread -> row ar, col-half ah (32 fp32)
    const int ar = tid >> 1;
    const int ah = tid & 1;
    const float* xrow = x + (size_t)(m0 + ar) * 256 + ah * 32;

    f32x4 acc[4][4] = {};
    f32x4 a0[4], a1[4];

    // ---- prologue: tile 0
#pragma unroll
    for (int j = 0; j < 4; ++j) {
        a0[j] = __builtin_nontemporal_load(reinterpret_cast<const f32x4*>(xrow + j * 8));
        a1[j] = __builtin_nontemporal_load(reinterpret_cast<const f32x4*>(xrow + j * 8 + 4));
    }
#pragma unroll
    for (int i = 0; i < 4; ++i)
        gl_lds16(w + (size_t)(n0 + i * 32 + srow) * 256 + 0 + scol,
                 &Bs[0][0][0] + i * 2048 + wave * 512);
    asm volatile("s_waitcnt vmcnt(0)" ::: "memory");
#pragma unroll
    for (int j = 0; j < 4; ++j) {
        bf16x8 o;
        o[0] = (__bf16)a0[j][0]; o[1] = (__bf16)a0[j][1]; o[2] = (__bf16)a0[j][2]; o[3] = (__bf16)a0[j][3];
        o[4] = (__bf16)a1[j][0]; o[5] = (__bf16)a1[j][1]; o[6] = (__bf16)a1[j][2]; o[7] = (__bf16)a1[j][3];
        *reinterpret_cast<bf16x8*>(&As[0][ar][(((ah * 4 + j) ^ (ar & 7)) << 3)]) = o;
    }
    __syncthreads();

#pragma unroll
    for (int t = 0; t < 4; ++t) {
        const int nxt = (t + 1) & 1;
        if (t < 3) {
            const int k0 = (t + 1) * 64;
#pragma unroll
            for (int j = 0; j < 4; ++j) {
                a0[j] = __builtin_nontemporal_load(reinterpret_cast<const f32x4*>(xrow + k0 + j * 8));
                a1[j] = __builtin_nontemporal_load(reinterpret_cast<const f32x4*>(xrow + k0 + j * 8 + 4));
            }
#pragma unroll
            for (int i = 0; i < 4; ++i)
                gl_lds16(w + (size_t)(n0 + i * 32 + srow) * 256 + k0 + scol,
                         &Bs[nxt][0][0] + i * 2048 + wave * 512);
        }
        const __bf16* Ab = &As[t & 1][0][0];
        const __bf16* Bb = &Bs[t & 1][0][0];
        __builtin_amdgcn_s_setprio(1);
#pragma unroll
        for (int kk = 0; kk < 64; kk += 32) {
            const int cl = (kk >> 3) + quad;      // logical c16
            bf16x8 af[4], bfr[4];
#pragma unroll
            for (int mt = 0; mt < 4; ++mt) {
                int row = wm * 64 + mt * 16 + lm;
                af[mt] = *reinterpret_cast<const bf16x8*>(Ab + row * 64 + ((cl ^ (lm & 7)) << 3));
            }
#pragma unroll
            for (int nt = 0; nt < 4; ++nt) {
                int row = wn * 64 + nt * 16 + lm;
                bfr[nt] = *reinterpret_cast<const bf16x8*>(Bb + row * 64 + ((cl ^ (lm & 7)) << 3));
            }
#pragma unroll
            for (int mt = 0; mt < 4; ++mt)
#pragma unroll
                for (int nt = 0; nt < 4; ++nt)
                    acc[mt][nt] = __builtin_amdgcn_mfma_f32_16x16x32_bf16(af[mt], bfr[nt], acc[mt][nt], 0, 0, 0);
        }
        __builtin_amdgcn_s_setprio(0);
        asm volatile("s_waitcnt vmcnt(0)" ::: "memory");
        if (t < 3) {
#pragma unroll
            for (int j = 0; j < 4; ++j) {
                bf16x8 o;
                o[0] = (__bf16)a0[j][0]; o[1] = (__bf16)a0[j][1]; o[2] = (__bf16)a0[j][2]; o[3] = (__bf16)a0[j][3];
                o[4] = (__bf16)a1[j][0]; o[5] = (__bf16)a1[j][1]; o[6] = (__bf16)a1[j][2]; o[7] = (__bf16)a1[j][3];
                *reinterpret_cast<bf16x8*>(&As[nxt][ar][(((ah * 4 + j) ^ (ar & 7)) << 3)]) = o;
            }
        }
        __syncthreads();
    }

    // ---- epilogue: restage C tile (bf16) through LDS, then coalesced NT stores.
    // Cs spans As[0..1] (32KB, both buffers dead); XOR (row&0xC)<<2 avoids
    // quad-aliasing on the scalar writes.
    const int   c3   = n0 >> 8;
    const float scl  = (c3 == 0) ? 0.17677669529663687f : 1.0f;
    __bf16*     segp = ws + (size_t)c3 * SEG;
    const int   n0c  = n0 & 255;
    char*       Cs   = (char*)&As[0][0][0];

#pragma unroll
    for (int nt = 0; nt < 4; ++nt) {
        float bj = bvec[n0 + wn * 64 + nt * 16 + lm];
#pragma unroll
        for (int mt = 0; mt < 4; ++mt)
#pragma unroll
            for (int r = 0; r < 4; ++r) {
                int row = wm * 64 + mt * 16 + quad * 4 + r;
                int byteoff = (row << 8) + ((wn * 64 + nt * 16 + lm) << 1);
                byteoff ^= (row & 0xC) << 2;
                *reinterpret_cast<__bf16*>(Cs + byteoff) =
                    (__bf16)((acc[mt][nt][r] + bj) * scl);
            }
    }
    __syncthreads();
#pragma unroll
    for (int it = 0; it < 8; ++it) {
        int row = it * 16 + (tid >> 4);
        int byteoff = (row << 8) + ((tid & 15) << 4);
        byteoff ^= (row & 0xC) << 2;
        bf16x8 c8 = *reinterpret_cast<const bf16x8*>(Cs + byteoff);
        __builtin_nontemporal_store(c8,
            reinterpret_cast<bf16x8*>(segp + (size_t)(m0 + row) * 256 + n0c + ((tid & 15) << 3)));
    }
}

// ---------------------------------------------------------------------------
// K2: MFMA attention. One wave (64 threads) per (window, head).
//   q/k/v segments are (M,256) with c = h*32+d; row stride 256 elems.
//   S^T = K·Q^T (16 mfma) -> +ADD -> in-register softmax -> P to LDS (bf16)
//   -> out = P·V (16 mfma, V transposed into LDS) -> restage O via LDS ->
//   coalesced 64B-segment stores to pre (B_,N,C) bf16.
// ---------------------------------------------------------------------------
__global__ __launch_bounds__(64)
void attn_mfma_k(const __bf16* __restrict__ ws, const float* __restrict__ add,
                 __bf16* __restrict__ pre)
{
    __shared__ __bf16 Pl[64 * 72];   // P[i][j], row stride 72 (2-way bank alias = free)
    __shared__ __bf16 Vt[32 * 72];   // V^T[d][j]; reused as O[64][32] at the end
    const int lane = threadIdx.x;
    const int bh   = blockIdx.x;                 // b*8 + h
    const int b    = bh >> 3, h = bh & 7;
    const int wh   = ((b & 63) << 3) | h;
    const int quad = lane >> 4, lm = lane & 15;
    const int koff = quad * 8;

    // row i of this window = global row b*49+i; head column block = h*32
    const __bf16* qp = ws + (size_t)(b * 49) * 256 + h * 32;
    const __bf16* kp = qp + SEG;
    const __bf16* vp = qp + (size_t)2 * SEG;

    // ---- zero V^T pad rows j=48..63 (j=48 overwritten below; j>=49 must be
    // exactly representable-finite so P(=0)*Vt can't make NaN)
    {
        int d = lane >> 1, j0 = 48 + (lane & 1) * 8;
        *reinterpret_cast<bf16x8*>(&Vt[d * 72 + j0]) = bzero8();
    }
    // ---- transpose V (49x32) into Vt
#pragma unroll
    for (int t = 0; t < 4; ++t) {
        int idx = lane + t * 64;
        if (idx < 196) {
            int j = idx >> 2, c8 = (idx & 3) * 8;
            bf16x8 vv = *reinterpret_cast<const bf16x8*>(vp + j * 256 + c8);
#pragma unroll
            for (int u = 0; u < 8; ++u) Vt[(c8 + u) * 72 + j] = vv[u];
        }
    }

    // ---- Q (B-operand, col=i) unpredicated (rows >=49 read into next seg —
    // in-bounds of ws, values never used); K (A-operand, row=j) zero-padded
    bf16x8 qf[4], kf[4];
#pragma unroll
    for (int t = 0; t < 4; ++t)
        qf[t] = *reinterpret_cast<const bf16x8*>(qp + (t * 16 + lm) * 256 + koff);
#pragma unroll
    for (int t = 0; t < 4; ++t) {
        int m = t * 16 + lm;
        kf[t] = (m < 49) ? *reinterpret_cast<const bf16x8*>(kp + m * 256 + koff)
                         : bzero8();
    }

    // ---- S^T = K·Q^T : s[mt][nt], rows j = mt*16+quad*4+r, cols i = nt*16+lm
    f32x4 s[4][4] = {};
#pragma unroll
    for (int mt = 0; mt < 4; ++mt)
#pragma unroll
        for (int nt = 0; nt < 4; ++nt)
            s[mt][nt] = __builtin_amdgcn_mfma_f32_16x16x32_bf16(kf[mt], qf[nt], s[mt][nt], 0, 0, 0);

    // ---- + (mask+bias), layout ADD[wh][i][j]: regs = 4 consecutive j
    const float* ap = add + (size_t)wh * 4096;
#pragma unroll
    for (int nt = 0; nt < 4; ++nt) {
        int i = nt * 16 + lm;
#pragma unroll
        for (int mt = 0; mt < 4; ++mt) {
            f32x4 a4 = *reinterpret_cast<const f32x4*>(ap + i * 64 + mt * 16 + quad * 4);
            s[mt][nt] += a4;
        }
    }

    // ---- softmax over j (rows of S = i). Row i fixed per (nt,lm); j spread
    // over mt, reg, and quad -> in-register reduce + shfl_xor(16,32).
#pragma unroll
    for (int nt = 0; nt < 4; ++nt) {
        float mx = -3.0e38f;
#pragma unroll
        for (int mt = 0; mt < 4; ++mt)
#pragma unroll
            for (int r = 0; r < 4; ++r) mx = fmaxf(mx, s[mt][nt][r]);
        mx = fmaxf(mx, __shfl_xor(mx, 16));
        mx = fmaxf(mx, __shfl_xor(mx, 32));
        float sum = 0.f;
#pragma unroll
        for (int mt = 0; mt < 4; ++mt)
#pragma unroll
            for (int r = 0; r < 4; ++r) {
                float e = __expf(s[mt][nt][r] - mx);
                s[mt][nt][r] = e; sum += e;
            }
        sum += __shfl_xor(sum, 16);
        sum += __shfl_xor(sum, 32);
        float rl = 1.0f / sum;
#pragma unroll
        for (int mt = 0; mt < 4; ++mt)
#pragma unroll
            for (int r = 0; r < 4; ++r) s[mt][nt][r] *= rl;
    }

    // ---- P -> LDS, Pl[i][j]: 4 consecutive j per reg -> b64 stores
#pragma unroll
    for (int nt = 0; nt < 4; ++nt) {
        int i = nt * 16 + lm;
#pragma unroll
        for (int mt = 0; mt < 4; ++mt) {
            bf16x4 p4;
#pragma unroll
            for (int r = 0; r < 4; ++r) p4[r] = (__bf16)s[mt][nt][r];
            *reinterpret_cast<bf16x4*>(&Pl[i * 72 + mt * 16 + quad * 4]) = p4;
        }
    }
    __syncthreads();

    // ---- out = P·V : A = P rows i (ds_read_b128), B = V^T rows d
    f32x4 o[4][2] = {};
#pragma unroll
    for (int kt = 0; kt < 2; ++kt) {
        bf16x8 vf[2];
#pragma unroll
        for (int dt = 0; dt < 2; ++dt)
            vf[dt] = *reinterpret_cast<const bf16x8*>(&Vt[(dt * 16 + lm) * 72 + kt * 32 + koff]);
#pragma unroll
        for (int mt2 = 0; mt2 < 4; ++mt2) {
            bf16x8 pf = *reinterpret_cast<const bf16x8*>(&Pl[(mt2 * 16 + lm) * 72 + kt * 32 + koff]);
#pragma unroll
            for (int dt = 0; dt < 2; ++dt)
                o[mt2][dt] = __builtin_amdgcn_mfma_f32_16x16x32_bf16(pf, vf[dt], o[mt2][dt], 0, 0, 0);
        }
    }

    // ---- restage O through LDS (reuse Vt as [64][32]) -> coalesced stores:
    // 4 lanes x 16B = 64B contiguous (full sector) per row, 16 rows per instr.
    __syncthreads();                     // all Vt reads complete before reuse
    __bf16* Ol = &Vt[0];
#pragma unroll
    for (int mt2 = 0; mt2 < 4; ++mt2)
#pragma unroll
        for (int dt = 0; dt < 2; ++dt)
#pragma unroll
            for (int r = 0; r < 4; ++r)
                Ol[(mt2 * 16 + quad * 4 + r) * 32 + dt * 16 + lm] = (__bf16)o[mt2][dt][r];
    __syncthreads();
#pragma unroll
    for (int it = 0; it < 4; ++it) {
        int i = it * 16 + (lane >> 2);
        if (i < 49) {
            bf16x8 v8 = *reinterpret_cast<const bf16x8*>(&Ol[i * 32 + (lane & 3) * 8]);
            *reinterpret_cast<bf16x8*>(pre + ((size_t)(b * 49 + i)) * 256 + h * 32 + (lane & 3) * 8) = v8;
        }
    }
}

// ---------------------------------------------------------------------------
// K3: out = pre @ proj_wb^T + proj_b (fp32 out). M=200704, K=256, N=256.
// Same dbuf+swizzle structure as prior rounds; out stores NON-TEMPORAL
// (205MB stream, never re-read). Grid: flat 3136, XCD-chunked, n fastest.
// ---------------------------------------------------------------------------
__global__ __launch_bounds__(256)
void proj_gemm_k(const __bf16* __restrict__ pre, const __bf16* __restrict__ w,
                 const float* __restrict__ bvec, float* __restrict__ out)
{
    __shared__ __bf16 As[2][128][64];
    __shared__ __bf16 Bs[2][128][64];
    const int tid  = threadIdx.x;
    const int nwg  = 1568 * 2;                     // 3136, % 8 == 0
    const int bid  = blockIdx.x;
    const int v    = (bid & 7) * (nwg >> 3) + (bid >> 3);
    const int mb   = v >> 1, nb = v & 1;
    const int m0   = mb * 128;
    const int n0   = nb * 128;
    const int wave = tid >> 6, lane = tid & 63;
    const int wm   = wave >> 1, wn = wave & 1;
    const int quad = lane >> 4, lm = lane & 15;

    const int srow = wave * 8 + (lane >> 3);
    const int scol = (((lane & 7) ^ (lane >> 3)) << 3);

    f32x4 acc[4][4] = {};

#pragma unroll
    for (int i = 0; i < 4; ++i) {
        int row = i * 32 + srow;
        gl_lds16(pre + (size_t)(m0 + row) * 256 + 0 + scol,
                 &As[0][0][0] + i * 2048 + wave * 512);
        gl_lds16(w + (size_t)(n0 + row) * 256 + 0 + scol,
                 &Bs[0][0][0] + i * 2048 + wave * 512);
    }
    asm volatile("s_waitcnt vmcnt(0)" ::: "memory");
    __builtin_amdgcn_s_barrier();

#pragma unroll
    for (int t = 0; t < 4; ++t) {
        if (t < 3) {
            const int k0 = (t + 1) * 64;
            const int nb2 = (t + 1) & 1;
#pragma unroll
            for (int i = 0; i < 4; ++i) {
                int row = i * 32 + srow;
                gl_lds16(pre + (size_t)(m0 + row) * 256 + k0 + scol,
                         &As[nb2][0][0] + i * 2048 + wave * 512);
                gl_lds16(w + (size_t)(n0 + row) * 256 + k0 + scol,
                         &Bs[nb2][0][0] + i * 2048 + wave * 512);
            }
        }
        const __bf16* Ab = &As[t & 1][0][0];
        const __bf16* Bb = &Bs[t & 1][0][0];
        __builtin_amdgcn_s_setprio(1);
#pragma unroll
        for (int kk = 0; kk < 64; kk += 32) {
            const int cl = (kk >> 3) + quad;
            bf16x8 af[4], bfr[4];
#pragma unroll
            for (int mt = 0; mt < 4; ++mt) {
                int row = wm * 64 + mt * 16 + lm;
                af[mt] = *reinterpret_cast<const bf16x8*>(Ab + row * 64 + ((cl ^ (lm & 7)) << 3));
            }
#pragma unroll
            for (int nt = 0; nt < 4; ++nt) {
                int row = wn * 64 + nt * 16 + lm;
                bfr[nt] = *reinterpret_cast<const bf16x8*>(Bb + row * 64 + ((cl ^ (lm & 7)) << 3));
            }
#pragma unroll
            for (int mt = 0; mt < 4; ++mt)
#pragma unroll
                for (int nt = 0; nt < 4; ++nt)
                    acc[mt][nt] = __builtin_amdgcn_mfma_f32_16x16x32_bf16(af[mt], bfr[nt], acc[mt][nt], 0, 0, 0);
        }
        __builtin_amdgcn_s_setprio(0);
        asm volatile("s_waitcnt vmcnt(0)" ::: "memory");
        __builtin_amdgcn_s_barrier();
    }

#pragma unroll
    for (int nt = 0; nt < 4; ++nt) {
        int j = n0 + wn*64 + nt*16 + lm;
        float bj = bvec[j];
#pragma unroll
        for (int mt = 0; mt < 4; ++mt)
#pragma unroll
            for (int r = 0; r < 4; ++r) {
                int m = m0 + wm*64 + mt*16 + quad*4 + r;
                __builtin_nontemporal_store(acc[mt][nt][r] + bj, &out[(size_t)m*256 + j]);
            }
    }
}

extern "C" void kernel_launch(void* const* d_in, const int* in_sizes, int n_in,
                              void* d_out, int out_size, void* d_ws, size_t ws_size,
                              hipStream_t stream)
{
    const float* x      = (const float*)d_in[0];
    const float* mask   = (const float*)d_in[1];
    const float* qkv_w  = (const float*)d_in[2];
    const float* qkv_b  = (const float*)d_in[3];
    const float* proj_w = (const float*)d_in[4];
    const float* proj_b = (const float*)d_in[5];
    const float* rpb    = (const float*)d_in[6];

    __bf16* ws  = (__bf16*)d_ws;                 // 4*SEG*2 = 411 MB
    __bf16* pre = ws + (size_t)3 * SEG;
    float*  out = (float*)d_out;

    char*   ob      = (char*)d_out;
    float*  addbuf  = (float*)ob;                        // [0, 8.39MB)
    __bf16* qkv_wb  = (__bf16*)(ob + (10u << 20));       // 768x256 bf16
    __bf16* proj_wb = ws;                                // q segment, dead after attn

    cvt_bf16_k<<<dim3(96),   256, 0, stream>>>(qkv_w, qkv_wb, 196608 / 8);
    expand_add_k<<<dim3(512), 256, 0, stream>>>(mask, rpb, addbuf);
    qkv_gemm_k<<<dim3(1568 * 6), 256, 0, stream>>>(x, qkv_wb, qkv_b, ws);
    attn_mfma_k<<<dim3(32768), 64, 0, stream>>>(ws, addbuf, pre);
    cvt_bf16_k<<<dim3(32),   256, 0, stream>>>(proj_w, proj_wb, 65536 / 8);
    proj_gemm_k<<<dim3(1568 * 2), 256, 0, stream>>>(pre, proj_wb, proj_b, out);
}

// Round 8
// 741.726 us; speedup vs baseline: 1.3048x; 1.3048x over previous
//
#include <hip/hip_runtime.h>

// WindowAttention: B_=4096, N=49, C=256, H=8, hd=32, nW=64
// ws layout (bf16): [q | k | v | pre] each SEG elements
//   q/k/v: plain (M=200704, 256) row-major, m = b*49+i, c = h*32+d
//   pre  : (B_, N, C) attention output before proj
// d_out doubles as scratch:
//   [0, 8.39MB)  : expanded (mask+bias) ADD tensor (nW*H, 64, 64) fp32
//   [10MB, ...)  : qkv_w converted to bf16 (768x256)
//   [16MB, ...)  : x converted to bf16 (200704x256, 102.8MB)
// proj_gemm fully overwrites d_out afterwards and reads none of it.
// proj_w (bf16) is converted AFTER attn into ws segment 0 (q, dead by then).
#define SEG 51380224  // 4096*8*49*32 == 4096*49*256

typedef __attribute__((ext_vector_type(8))) __bf16 bf16x8;
typedef __attribute__((ext_vector_type(4))) __bf16 bf16x4;
typedef __attribute__((ext_vector_type(4))) float f32x4;

static __device__ __forceinline__ bf16x8 bzero8() {
    bf16x8 z;
#pragma unroll
    for (int u = 0; u < 8; ++u) z[u] = (__bf16)0.0f;
    return z;
}

// async global->LDS, 16B per lane; LDS dest is wave-uniform base + lane*16
static __device__ __forceinline__ void gl_lds16(const __bf16* g, __bf16* l) {
    __builtin_amdgcn_global_load_lds(
        (const __attribute__((address_space(1))) void*)g,
        (__attribute__((address_space(3))) void*)l, 16, 0, 0);
}

static __device__ __forceinline__ void cvt8(const float* src, __bf16* dst, int i) {
    float4 a = *reinterpret_cast<const float4*>(src + (size_t)i * 8);
    float4 b = *reinterpret_cast<const float4*>(src + (size_t)i * 8 + 4);
    bf16x8 o;
    o[0] = (__bf16)a.x; o[1] = (__bf16)a.y; o[2] = (__bf16)a.z; o[3] = (__bf16)a.w;
    o[4] = (__bf16)b.x; o[5] = (__bf16)b.y; o[6] = (__bf16)b.z; o[7] = (__bf16)b.w;
    *reinterpret_cast<bf16x8*>(dst + (size_t)i * 8) = o;
}

// ---------------------------------------------------------------------------
// P0: fused prep — cvt x (fp32->bf16), cvt qkv_w, expand ADD. One launch.
// ---------------------------------------------------------------------------
__global__ __launch_bounds__(256)
void prep_k(const float* __restrict__ x, __bf16* __restrict__ xb,
            const float* __restrict__ qw, __bf16* __restrict__ qwb,
            const float* __restrict__ mask, const float* __restrict__ rpb,
            float* __restrict__ add)
{
    const int NX = 51380224 / 8;          // x 8-elem groups
    const int NW = 196608 / 8;            // qkv_w groups
    const int NE = 2097152 / 8;           // ADD groups (8 consecutive j)
    int idx = blockIdx.x * 256 + threadIdx.x;
    const int stride = gridDim.x * 256;
    for (; idx < NX + NW + NE; idx += stride) {
        if (idx < NX) {
            cvt8(x, xb, idx);
        } else if (idx < NX + NW) {
            cvt8(qw, qwb, idx - NX);
        } else {
            int e = (idx - NX - NW) * 8;
            int wh = e >> 12, within = e & 4095;
            int i = within >> 6, j0 = within & 63;
            int w = wh >> 3, h = wh & 7;
            int ih = i / 7, iw = i - ih * 7;
            float o[8];
#pragma unroll
            for (int u = 0; u < 8; ++u) {
                int j = j0 + u;
                float v = -1e30f;
                if (i < 49 && j < 49) {
                    int jh = j / 7, jw = j - jh * 7;
                    int bidx = (ih - jh + 6) * 13 + (iw - jw + 6);
                    v = mask[(size_t)w * 2401 + i * 49 + j] + rpb[bidx * 8 + h];
                }
                o[u] = v;
            }
            float* dst = add + (size_t)wh * 4096 + i * 64 + j0;
            *reinterpret_cast<f32x4*>(dst)     = f32x4{o[0], o[1], o[2], o[3]};
            *reinterpret_cast<f32x4*>(dst + 4) = f32x4{o[4], o[5], o[6], o[7]};
        }
    }
}

// ---------------------------------------------------------------------------
// K-1: fp32 -> bf16 bulk convert (proj_w only).
// ---------------------------------------------------------------------------
__global__ __launch_bounds__(256)
void cvt_bf16_k(const float* __restrict__ src, __bf16* __restrict__ dst, int n8)
{
    int i = blockIdx.x * 256 + threadIdx.x;
    const int stride = gridDim.x * 256;
    for (; i < n8; i += stride) cvt8(src, dst, i);
}

// ---------------------------------------------------------------------------
// K1: qkv = xb @ qkv_wb^T + qkv_b -> three (M,256) bf16 segments.
// 128x128 tile, BK=32 dbuf (32KB LDS total -> 5 blocks/CU, ~62% occupancy:
// the concurrency lever — 2.5x more in-flight loads to hide L3/HBM latency).
// T2 swizzle for the 64B-row tile: source col ((l&3)^((l>>2)&3))<<3; read col
// (quad^(lm&3))<<3 — 2-way on read (free).
// Epilogue: LDS-restaged coalesced 256B-segment NT stores (output stream only).
// Grid: flat 9408; XCD-chunked bijective swizzle, n fastest (L2 panel reuse).
// ---------------------------------------------------------------------------
__global__ __launch_bounds__(256)
void qkv_gemm_k(const __bf16* __restrict__ x, const __bf16* __restrict__ w,
                const float* __restrict__ bvec, __bf16* __restrict__ ws)
{
    __shared__ __attribute__((aligned(16))) char smem[32768];
    __bf16* Asm = (__bf16*)smem;              // 2 x 4096 elems (8KB each)
    __bf16* Bsm = (__bf16*)(smem + 16384);
    const int tid  = threadIdx.x;
    const int nwg  = 1568 * 6;                     // 9408, % 8 == 0
    const int bid  = blockIdx.x;
    const int v    = (bid & 7) * (nwg >> 3) + (bid >> 3);
    const int mb   = v / 6, nb = v - mb * 6;
    const int m0   = mb * 128;
    const int n0   = nb * 128;
    const int wave = tid >> 6, lane = tid & 63;
    const int wm   = wave >> 1, wn = wave & 1;
    const int quad = lane >> 4, lm = lane & 15;

    // staging: issue i covers rows [i*64 + wave*16, +16); lane l -> row +l/4,
    // source col pre-swizzled so phys c8 = logical ^ (row&3).
    const int srow = wave * 16 + (lane >> 2);
    const int scol = (((lane & 3) ^ ((lane >> 2) & 3)) << 3);

    f32x4 acc[4][4] = {};

    // prologue: stage k-tile 0 into buf 0
#pragma unroll
    for (int i = 0; i < 2; ++i) {
        gl_lds16(x + (size_t)(m0 + i * 64 + srow) * 256 + 0 + scol,
                 Asm + i * 2048 + wave * 512);
        gl_lds16(w + (size_t)(n0 + i * 64 + srow) * 256 + 0 + scol,
                 Bsm + i * 2048 + wave * 512);
    }
    asm volatile("s_waitcnt vmcnt(0)" ::: "memory");
    __builtin_amdgcn_s_barrier();

#pragma unroll
    for (int t = 0; t < 8; ++t) {
        const int cur = t & 1, nxt = cur ^ 1;
        if (t < 7) {
            const int k0 = (t + 1) * 32;
#pragma unroll
            for (int i = 0; i < 2; ++i) {
                gl_lds16(x + (size_t)(m0 + i * 64 + srow) * 256 + k0 + scol,
                         Asm + nxt * 4096 + i * 2048 + wave * 512);
                gl_lds16(w + (size_t)(n0 + i * 64 + srow) * 256 + k0 + scol,
                         Bsm + nxt * 4096 + i * 2048 + wave * 512);
            }
        }
        const __bf16* Ab = Asm + cur * 4096;
        const __bf16* Bb = Bsm + cur * 4096;
        __builtin_amdgcn_s_setprio(1);
        bf16x8 af[4], bfr[4];
#pragma unroll
        for (int mt = 0; mt < 4; ++mt) {
            int row = wm * 64 + mt * 16 + lm;
            af[mt] = *reinterpret_cast<const bf16x8*>(Ab + row * 32 + ((quad ^ (lm & 3)) << 3));
        }
#pragma unroll
        for (int nt = 0; nt < 4; ++nt) {
            int row = wn * 64 + nt * 16 + lm;
            bfr[nt] = *reinterpret_cast<const bf16x8*>(Bb + row * 32 + ((quad ^ (lm & 3)) << 3));
        }
#pragma unroll
        for (int mt = 0; mt < 4; ++mt)
#pragma unroll
            for (int nt = 0; nt < 4; ++nt)
                acc[mt][nt] = __builtin_amdgcn_mfma_f32_16x16x32_bf16(af[mt], bfr[nt], acc[mt][nt], 0, 0, 0);
        __builtin_amdgcn_s_setprio(0);
        asm volatile("s_waitcnt vmcnt(0)" ::: "memory");
        __builtin_amdgcn_s_barrier();
    }

    // ---- epilogue: restage C tile (bf16) through LDS (all 32KB now dead),
    // then coalesced 256B-segment NT stores.
    const int   c3   = n0 >> 8;
    const float scl  = (c3 == 0) ? 0.17677669529663687f : 1.0f;
    __bf16*     segp = ws + (size_t)c3 * SEG;
    const int   n0c  = n0 & 255;
    char*       Cs   = smem;

#pragma unroll
    for (int nt = 0; nt < 4; ++nt) {
        float bj = bvec[n0 + wn * 64 + nt * 16 + lm];
#pragma unroll
        for (int mt = 0; mt < 4; ++mt)
#pragma unroll
            for (int r = 0; r < 4; ++r) {
                int row = wm * 64 + mt * 16 + quad * 4 + r;
                int byteoff = (row << 8) + ((wn * 64 + nt * 16 + lm) << 1);
                byteoff ^= (row & 0xC) << 2;
                *reinterpret_cast<__bf16*>(Cs + byteoff) =
                    (__bf16)((acc[mt][nt][r] + bj) * scl);
            }
    }
    __syncthreads();
#pragma unroll
    for (int it = 0; it < 8; ++it) {
        int row = it * 16 + (tid >> 4);
        int byteoff = (row << 8) + ((tid & 15) << 4);
        byteoff ^= (row & 0xC) << 2;
        bf16x8 c8 = *reinterpret_cast<const bf16x8*>(Cs + byteoff);
        __builtin_nontemporal_store(c8,
            reinterpret_cast<bf16x8*>(segp + (size_t)(m0 + row) * 256 + n0c + ((tid & 15) << 3)));
    }
}

// ---------------------------------------------------------------------------
// K2: MFMA attention. One wave (64 threads) per (window, head). (round-5 form)
// ---------------------------------------------------------------------------
__global__ __launch_bounds__(64)
void attn_mfma_k(const __bf16* __restrict__ ws, const float* __restrict__ add,
                 __bf16* __restrict__ pre)
{
    __shared__ __bf16 Pl[64 * 72];   // P[i][j], row stride 72 (2-way alias = free)
    __shared__ __bf16 Vt[32 * 72];   // V^T[d][j]; reused as O[64][32] at the end
    const int lane = threadIdx.x;
    const int bh   = blockIdx.x;                 // b*8 + h
    const int b    = bh >> 3, h = bh & 7;
    const int wh   = ((b & 63) << 3) | h;
    const int quad = lane >> 4, lm = lane & 15;
    const int koff = quad * 8;

    const __bf16* qp = ws + (size_t)(b * 49) * 256 + h * 32;
    const __bf16* kp = qp + SEG;
    const __bf16* vp = qp + (size_t)2 * SEG;

    {
        int d = lane >> 1, j0 = 48 + (lane & 1) * 8;
        *reinterpret_cast<bf16x8*>(&Vt[d * 72 + j0]) = bzero8();
    }
#pragma unroll
    for (int t = 0; t < 4; ++t) {
        int idx = lane + t * 64;
        if (idx < 196) {
            int j = idx >> 2, c8 = (idx & 3) * 8;
            bf16x8 vv = *reinterpret_cast<const bf16x8*>(vp + j * 256 + c8);
#pragma unroll
            for (int u = 0; u < 8; ++u) Vt[(c8 + u) * 72 + j] = vv[u];
        }
    }

    bf16x8 qf[4], kf[4];
#pragma unroll
    for (int t = 0; t < 4; ++t)
        qf[t] = *reinterpret_cast<const bf16x8*>(qp + (t * 16 + lm) * 256 + koff);
#pragma unroll
    for (int t = 0; t < 4; ++t) {
        int m = t * 16 + lm;
        kf[t] = (m < 49) ? *reinterpret_cast<const bf16x8*>(kp + m * 256 + koff)
                         : bzero8();
    }

    f32x4 s[4][4] = {};
#pragma unroll
    for (int mt = 0; mt < 4; ++mt)
#pragma unroll
        for (int nt = 0; nt < 4; ++nt)
            s[mt][nt] = __builtin_amdgcn_mfma_f32_16x16x32_bf16(kf[mt], qf[nt], s[mt][nt], 0, 0, 0);

    const float* ap = add + (size_t)wh * 4096;
#pragma unroll
    for (int nt = 0; nt < 4; ++nt) {
        int i = nt * 16 + lm;
#pragma unroll
        for (int mt = 0; mt < 4; ++mt) {
            f32x4 a4 = *reinterpret_cast<const f32x4*>(ap + i * 64 + mt * 16 + quad * 4);
            s[mt][nt] += a4;
        }
    }

#pragma unroll
    for (int nt = 0; nt < 4; ++nt) {
        float mx = -3.0e38f;
#pragma unroll
        for (int mt = 0; mt < 4; ++mt)
#pragma unroll
            for (int r = 0; r < 4; ++r) mx = fmaxf(mx, s[mt][nt][r]);
        mx = fmaxf(mx, __shfl_xor(mx, 16));
        mx = fmaxf(mx, __shfl_xor(mx, 32));
        float sum = 0.f;
#pragma unroll
        for (int mt = 0; mt < 4; ++mt)
#pragma unroll
            for (int r = 0; r < 4; ++r) {
                float e = __expf(s[mt][nt][r] - mx);
                s[mt][nt][r] = e; sum += e;
            }
        sum += __shfl_xor(sum, 16);
        sum += __shfl_xor(sum, 32);
        float rl = 1.0f / sum;
#pragma unroll
        for (int mt = 0; mt < 4; ++mt)
#pragma unroll
            for (int r = 0; r < 4; ++r) s[mt][nt][r] *= rl;
    }

#pragma unroll
    for (int nt = 0; nt < 4; ++nt) {
        int i = nt * 16 + lm;
#pragma unroll
        for (int mt = 0; mt < 4; ++mt) {
            bf16x4 p4;
#pragma unroll
            for (int r = 0; r < 4; ++r) p4[r] = (__bf16)s[mt][nt][r];
            *reinterpret_cast<bf16x4*>(&Pl[i * 72 + mt * 16 + quad * 4]) = p4;
        }
    }
    __syncthreads();

    f32x4 o[4][2] = {};
#pragma unroll
    for (int kt = 0; kt < 2; ++kt) {
        bf16x8 vf[2];
#pragma unroll
        for (int dt = 0; dt < 2; ++dt)
            vf[dt] = *reinterpret_cast<const bf16x8*>(&Vt[(dt * 16 + lm) * 72 + kt * 32 + koff]);
#pragma unroll
        for (int mt2 = 0; mt2 < 4; ++mt2) {
            bf16x8 pf = *reinterpret_cast<const bf16x8*>(&Pl[(mt2 * 16 + lm) * 72 + kt * 32 + koff]);
#pragma unroll
            for (int dt = 0; dt < 2; ++dt)
                o[mt2][dt] = __builtin_amdgcn_mfma_f32_16x16x32_bf16(pf, vf[dt], o[mt2][dt], 0, 0, 0);
        }
    }

    __syncthreads();
    __bf16* Ol = &Vt[0];
#pragma unroll
    for (int mt2 = 0; mt2 < 4; ++mt2)
#pragma unroll
        for (int dt = 0; dt < 2; ++dt)
#pragma unroll
            for (int r = 0; r < 4; ++r)
                Ol[(mt2 * 16 + quad * 4 + r) * 32 + dt * 16 + lm] = (__bf16)o[mt2][dt][r];
    __syncthreads();
#pragma unroll
    for (int it = 0; it < 4; ++it) {
        int i = it * 16 + (lane >> 2);
        if (i < 49) {
            bf16x8 v8 = *reinterpret_cast<const bf16x8*>(&Ol[i * 32 + (lane & 3) * 8]);
            *reinterpret_cast<bf16x8*>(pre + ((size_t)(b * 49 + i)) * 256 + h * 32 + (lane & 3) * 8) = v8;
        }
    }
}

// ---------------------------------------------------------------------------
// K3: out = pre @ proj_wb^T + proj_b (fp32 out). Same BK=32 dbuf structure as
// K1 (32KB LDS -> 5 blocks/CU). NT fp32 stores (full sectors, never re-read).
// ---------------------------------------------------------------------------
__global__ __launch_bounds__(256)
void proj_gemm_k(const __bf16* __restrict__ pre, const __bf16* __restrict__ w,
                 const float* __restrict__ bvec, float* __restrict__ out)
{
    __shared__ __attribute__((aligned(16))) char smem[32768];
    __bf16* Asm = (__bf16*)smem;
    __bf16* Bsm = (__bf16*)(smem + 16384);
    const int tid  = threadIdx.x;
    const int nwg  = 1568 * 2;                     // 3136, % 8 == 0
    const int bid  = blockIdx.x;
    const int v    = (bid & 7) * (nwg >> 3) + (bid >> 3);
    const int mb   = v >> 1, nb = v & 1;
    const int m0   = mb * 128;
    const int n0   = nb * 128;
    const int wave = tid >> 6, lane = tid & 63;
    const int wm   = wave >> 1, wn = wave & 1;
    const int quad = lane >> 4, lm = lane & 15;

    const int srow = wave * 16 + (lane >> 2);
    const int scol = (((lane & 3) ^ ((lane >> 2) & 3)) << 3);

    f32x4 acc[4][4] = {};

#pragma unroll
    for (int i = 0; i < 2; ++i) {
        gl_lds16(pre + (size_t)(m0 + i * 64 + srow) * 256 + 0 + scol,
                 Asm + i * 2048 + wave * 512);
        gl_lds16(w + (size_t)(n0 + i * 64 + srow) * 256 + 0 + scol,
                 Bsm + i * 2048 + wave * 512);
    }
    asm volatile("s_waitcnt vmcnt(0)" ::: "memory");
    __builtin_amdgcn_s_barrier();

#pragma unroll
    for (int t = 0; t < 8; ++t) {
        const int cur = t & 1, nxt = cur ^ 1;
        if (t < 7) {
            const int k0 = (t + 1) * 32;
#pragma unroll
            for (int i = 0; i < 2; ++i) {
                gl_lds16(pre + (size_t)(m0 + i * 64 + srow) * 256 + k0 + scol,
                         Asm + nxt * 4096 + i * 2048 + wave * 512);
                gl_lds16(w + (size_t)(n0 + i * 64 + srow) * 256 + k0 + scol,
                         Bsm + nxt * 4096 + i * 2048 + wave * 512);
            }
        }
        const __bf16* Ab = Asm + cur * 4096;
        const __bf16* Bb = Bsm + cur * 4096;
        __builtin_amdgcn_s_setprio(1);
        bf16x8 af[4], bfr[4];
#pragma unroll
        for (int mt = 0; mt < 4; ++mt) {
            int row = wm * 64 + mt * 16 + lm;
            af[mt] = *reinterpret_cast<const bf16x8*>(Ab + row * 32 + ((quad ^ (lm & 3)) << 3));
        }
#pragma unroll
        for (int nt = 0; nt < 4; ++nt) {
            int row = wn * 64 + nt * 16 + lm;
            bfr[nt] = *reinterpret_cast<const bf16x8*>(Bb + row * 32 + ((quad ^ (lm & 3)) << 3));
        }
#pragma unroll
        for (int mt = 0; mt < 4; ++mt)
#pragma unroll
            for (int nt = 0; nt < 4; ++nt)
                acc[mt][nt] = __builtin_amdgcn_mfma_f32_16x16x32_bf16(af[mt], bfr[nt], acc[mt][nt], 0, 0, 0);
        __builtin_amdgcn_s_setprio(0);
        asm volatile("s_waitcnt vmcnt(0)" ::: "memory");
        __builtin_amdgcn_s_barrier();
    }

#pragma unroll
    for (int nt = 0; nt < 4; ++nt) {
        int j = n0 + wn*64 + nt*16 + lm;
        float bj = bvec[j];
#pragma unroll
        for (int mt = 0; mt < 4; ++mt)
#pragma unroll
            for (int r = 0; r < 4; ++r) {
                int m = m0 + wm*64 + mt*16 + quad*4 + r;
                __builtin_nontemporal_store(acc[mt][nt][r] + bj, &out[(size_t)m*256 + j]);
            }
    }
}

extern "C" void kernel_launch(void* const* d_in, const int* in_sizes, int n_in,
                              void* d_out, int out_size, void* d_ws, size_t ws_size,
                              hipStream_t stream)
{
    const float* x      = (const float*)d_in[0];
    const float* mask   = (const float*)d_in[1];
    const float* qkv_w  = (const float*)d_in[2];
    const float* qkv_b  = (const float*)d_in[3];
    const float* proj_w = (const float*)d_in[4];
    const float* proj_b = (const float*)d_in[5];
    const float* rpb    = (const float*)d_in[6];

    __bf16* ws  = (__bf16*)d_ws;                 // 4*SEG*2 = 411 MB
    __bf16* pre = ws + (size_t)3 * SEG;
    float*  out = (float*)d_out;

    char*   ob      = (char*)d_out;
    float*  addbuf  = (float*)ob;                        // [0, 8.39MB)
    __bf16* qkv_wb  = (__bf16*)(ob + (10u << 20));       // 768x256 bf16
    __bf16* xb      = (__bf16*)(ob + (16u << 20));       // 200704x256 bf16, 102.8MB
    __bf16* proj_wb = ws;                                // q segment, dead after attn

    prep_k<<<dim3(2048), 256, 0, stream>>>(x, xb, qkv_w, qkv_wb, mask, rpb, addbuf);
    qkv_gemm_k<<<dim3(1568 * 6), 256, 0, stream>>>(xb, qkv_wb, qkv_b, ws);
    attn_mfma_k<<<dim3(32768), 64, 0, stream>>>(ws, addbuf, pre);
    cvt_bf16_k<<<dim3(32),   256, 0, stream>>>(proj_w, proj_wb, 65536 / 8);
    proj_gemm_k<<<dim3(1568 * 2), 256, 0, stream>>>(pre, proj_wb, proj_b, out);
}